// Round 1
// baseline (12.041 us; speedup 1.0000x reference)
//
#include <hip/hip_runtime.h>

// Output row layout: [ basegraph[0..511] | x[b,i,10..19] | 30 zeros ] = 552 floats.
// basegraph[b,i,j] = exp(-((x[b,i,4]-x[b,j,4])^2 + (x[b,i,5]-x[b,j,5])^2))
// x shape: (8, 512, 20) fp32.

#define GS    512
#define TWO_P 20
#define P     10
#define FREE  30
#define ROWW  (GS + P + FREE)   // 552

__global__ __launch_bounds__(GS) void gbuilder_kernel(const float* __restrict__ x,
                                                      float* __restrict__ out) {
    const int row = blockIdx.x;          // b*512 + i
    const int b   = row >> 9;
    const int i   = row & (GS - 1);
    const int j   = threadIdx.x;

    const float* xb = x + (size_t)b * GS * TWO_P;

    // Broadcast read of row i's metric coords (columns 4,5 are adjacent, 8B-aligned).
    const float2 xi = *reinterpret_cast<const float2*>(xb + (size_t)i * TWO_P + 4);
    // Per-thread read of row j's metric coords.
    const float2 xj = *reinterpret_cast<const float2*>(xb + (size_t)j * TWO_P + 4);

    const float d4 = xi.x - xj.x;
    const float d5 = xi.y - xj.y;
    const float dsq = d4 * d4 + d5 * d5;

    float* orow = out + (size_t)row * ROWW;
    orow[j] = __expf(-dsq);

    // Tail: 10 parax values then 30 zeros (must write zeros: d_out is poisoned).
    if (j < P + FREE) {
        orow[GS + j] = (j < P) ? xb[(size_t)i * TWO_P + P + j] : 0.0f;
    }
}

extern "C" void kernel_launch(void* const* d_in, const int* in_sizes, int n_in,
                              void* d_out, int out_size, void* d_ws, size_t ws_size,
                              hipStream_t stream) {
    const float* x = (const float*)d_in[0];
    float* out = (float*)d_out;
    // B * gs = 8 * 512 = 4096 rows
    gbuilder_kernel<<<8 * GS, GS, 0, stream>>>(x, out);
}